// Round 3
// baseline (479.015 us; speedup 1.0000x reference)
//
#include <hip/hip_runtime.h>
#include <cstdint>
#include <cstddef>

// x: [512][64][1024], conv1: K=32 S=16 -> T=63, Cout=256
// z layout: [n][t][c] flat = (n*63+t)*256 + c
// fp16 2-limb: v ~= hi + lo*(1/2048), hi=fp16(v), lo=fp16((v-hi)*2048)

typedef _Float16 half8 __attribute__((ext_vector_type(8)));
typedef float floatx4 __attribute__((ext_vector_type(4)));

__device__ __forceinline__ void split_f32(float v, _Float16& hi, _Float16& lo) {
    _Float16 h = (_Float16)v;
    hi = h;
    lo = (_Float16)((v - (float)h) * 2048.0f);
}

// global -> LDS direct DMA, 16B per lane (wave-uniform LDS base + lane*16)
typedef const __attribute__((address_space(1))) unsigned int* gas_ptr;
typedef __attribute__((address_space(3))) unsigned int* las_ptr;
__device__ __forceinline__ void lds_dma16(const void* g, void* l) {
    __builtin_amdgcn_global_load_lds((gas_ptr)g, (las_ptr)l, 16, 0, 0);
}

// counted-vmcnt barrier: leaves the N newest VMEM ops in flight (T4: never drain to 0
// in the steady state). Single asm block so nothing reorders between wait and barrier.
#define BARRIER_VM(N) asm volatile("s_waitcnt vmcnt(" #N ") lgkmcnt(0)\n\ts_barrier" ::: "memory")

// ---------------------------------------------------------------------------
// K0: prep — BN fold, fp16 limb splits of conv1_w, conv2_w(T), w1 (dense1)
// ---------------------------------------------------------------------------
__global__ __launch_bounds__(256) void prep_kernel(
    const float* __restrict__ c1w, const float* __restrict__ c1b,
    const float* __restrict__ g1,  const float* __restrict__ b1,
    const float* __restrict__ m1,  const float* __restrict__ v1,
    const float* __restrict__ c2w, const float* __restrict__ c2b,
    const float* __restrict__ g2,  const float* __restrict__ b2,
    const float* __restrict__ m2,  const float* __restrict__ v2,
    const float* __restrict__ w1,
    _Float16* __restrict__ w1h, _Float16* __restrict__ w1l,
    _Float16* __restrict__ w2h, _Float16* __restrict__ w2l,
    _Float16* __restrict__ wdh, _Float16* __restrict__ wdl,
    float* __restrict__ ab1, float* __restrict__ ab2)
{
    const int id = blockIdx.x * 256 + threadIdx.x;   // 65536 total
    if (id < 256) {
        float a1 = g1[id] / sqrtf(v1[id] + 1e-5f);
        ab1[id]       = a1;
        ab1[256 + id] = (c1b[id] - m1[id]) * a1 + b1[id];
        float a2 = g2[id] / sqrtf(v2[id] + 1e-5f);
        ab2[id]       = a2;
        ab2[256 + id] = (c2b[id] - m2[id]) * a2 + b2[id];
    }
    // dense1 weights: w1[o][c] row-major already == B-row layout [o][k=c]
    split_f32(w1[id], wdh[id], wdl[id]);
    // conv1_w limbs: [o][2048] direct layout
    for (int idx = id; idx < 256 * 2048; idx += 65536)
        split_f32(c1w[idx], w1h[idx], w1l[idx]);
    // conv2_w limbs transposed to [o][dt*256+c]
    for (int idx = id; idx < 256 * 768; idx += 65536) {
        const int o  = idx / 768;
        const int r  = idx - o * 768;
        const int dt = r >> 8;
        const int c  = r & 255;
        split_f32(c2w[o * 768 + c * 3 + dt], w2h[idx], w2l[idx]);
    }
}

// ---------------------------------------------------------------------------
// K1: conv1 + bn1, fp16 2-limb MFMA GEMM. M=32256, K=2048 (c*32+k), N=256.
// 128x128 tile, dbuf LDS, raw s_barrier + counted vmcnt(4):
//   per iter issue order (pinned): [B-DMA(it+1) x4] [A-loads(it+2) x4]
//   barrier waits vmcnt(4) -> B-DMA done, A-loads (HBM-cold) stay in flight
//   across the barrier with ~1.5 iterations of latency cover.
// ---------------------------------------------------------------------------
__global__ __launch_bounds__(256, 2) void conv1_mfma(
    const float* __restrict__ x,
    const _Float16* __restrict__ w1h, const _Float16* __restrict__ w1l,
    const float* __restrict__ ab,
    _Float16* __restrict__ z1h, _Float16* __restrict__ z1l)
{
    __shared__ _Float16 Ah[2][4][128][8];   // [buf][k-quad][m][8] fragment-major
    __shared__ _Float16 Al[2][4][128][8];
    __shared__ _Float16 Bh[2][4][128][8];
    __shared__ _Float16 Bl[2][4][128][8];

    const int tid = threadIdx.x;
    const int bm = blockIdx.x, bn = blockIdx.y;
    const int lr = tid & 127;
    const int h  = tid >> 7;

    const int am = bm * 128 + lr;
    const int an = am / 63, at = am - an * 63;
    const float* arow = x + (size_t)an * 65536 + at * 16 + h * 16;

    const int lane = tid & 63;
    const int wv   = tid >> 6;
    const int mw   = wv & 1, nw = wv >> 1;
    const int quad = lane >> 4;
    const int l15  = lane & 15;

    // B DMA assignment: wave wv stages quads {q0, q0+2} of row-half (wv&1)
    const int q0 = wv >> 1;
    const int rh = (wv & 1) * 64;
    const _Float16* bh_g = w1h + (size_t)(bn * 128 + rh + lane) * 2048;
    const _Float16* bl_g = w1l + (size_t)(bn * 128 + rh + lane) * 2048;

    floatx4 accA[4][4] = {};
    floatx4 accB[4][4] = {};

    union U { _Float16 hf[8]; int4 v; };
    float va0[16], va1[16];   // A prefetch, depth 2, statically indexed

    // ---- prologue ----
    {
        // B DMA tile0 (oldest VMEM)
        lds_dma16(bh_g + q0 * 8,       &Bh[0][q0    ][rh][0]);
        lds_dma16(bh_g + (q0 + 2) * 8, &Bh[0][q0 + 2][rh][0]);
        lds_dma16(bl_g + q0 * 8,       &Bl[0][q0    ][rh][0]);
        lds_dma16(bl_g + (q0 + 2) * 8, &Bl[0][q0 + 2][rh][0]);
        __builtin_amdgcn_sched_barrier(0);
        // A tile0 -> va0, A tile1 -> va1
        *(float4*)&va0[0]  = *(const float4*)(arow);
        *(float4*)&va0[4]  = *(const float4*)(arow + 4);
        *(float4*)&va0[8]  = *(const float4*)(arow + 8);
        *(float4*)&va0[12] = *(const float4*)(arow + 12);
        const float* ap1 = arow + 1024;
        *(float4*)&va1[0]  = *(const float4*)(ap1);
        *(float4*)&va1[4]  = *(const float4*)(ap1 + 4);
        *(float4*)&va1[8]  = *(const float4*)(ap1 + 8);
        *(float4*)&va1[12] = *(const float4*)(ap1 + 12);
        // split tile0 -> buf0 (compiler auto-waits va0; va1 stays in flight)
        U c0h, c0l, c1h, c1l;
#pragma unroll
        for (int j = 0; j < 8; ++j) split_f32(va0[j],     c0h.hf[j], c0l.hf[j]);
#pragma unroll
        for (int j = 0; j < 8; ++j) split_f32(va0[8 + j], c1h.hf[j], c1l.hf[j]);
        *(int4*)&Ah[0][2*h  ][lr][0] = c0h.v;
        *(int4*)&Ah[0][2*h+1][lr][0] = c1h.v;
        *(int4*)&Al[0][2*h  ][lr][0] = c0l.v;
        *(int4*)&Al[0][2*h+1][lr][0] = c1l.v;
        BARRIER_VM(4);   // B-DMA(0) drained; va1's 4 loads remain in flight
    }

    // body for one iteration; cur/nxt compile-time via unroll-by-2.
    auto body = [&](int it, float (&vaC)[16], float (&vaN)[16], int cur) {
        const int nxt = cur ^ 1;
        // B DMA for tile it+1 (must complete by end-of-iter barrier)
        if (it + 1 < 64) {
            const int ko = (it + 1) * 32;
            lds_dma16(bh_g + ko + q0 * 8,       &Bh[nxt][q0    ][rh][0]);
            lds_dma16(bh_g + ko + (q0 + 2) * 8, &Bh[nxt][q0 + 2][rh][0]);
            lds_dma16(bl_g + ko + q0 * 8,       &Bl[nxt][q0    ][rh][0]);
            lds_dma16(bl_g + ko + (q0 + 2) * 8, &Bl[nxt][q0 + 2][rh][0]);
        }
        __builtin_amdgcn_sched_barrier(0);
        // A loads for tile it+2 (newest; allowed to stay in flight at barrier)
        if (it + 2 < 64) {
            const float* ap = arow + (it + 2) * 1024;
            *(float4*)&vaC[0]  = *(const float4*)(ap);
            *(float4*)&vaC[4]  = *(const float4*)(ap + 4);
            *(float4*)&vaC[8]  = *(const float4*)(ap + 8);
            *(float4*)&vaC[12] = *(const float4*)(ap + 12);
        }
        __builtin_amdgcn_sched_barrier(0);

        // compute on buf[cur]
        half8 fah[4], fal[4], fbh[4], fbl[4];
#pragma unroll
        for (int t = 0; t < 4; ++t) {
            fah[t] = *(const half8*)&Ah[cur][quad][mw*64 + t*16 + l15][0];
            fal[t] = *(const half8*)&Al[cur][quad][mw*64 + t*16 + l15][0];
            fbh[t] = *(const half8*)&Bh[cur][quad][nw*64 + t*16 + l15][0];
            fbl[t] = *(const half8*)&Bl[cur][quad][nw*64 + t*16 + l15][0];
        }
#pragma unroll
        for (int ti = 0; ti < 4; ++ti)
#pragma unroll
            for (int tj = 0; tj < 4; ++tj) {
                accA[ti][tj] = __builtin_amdgcn_mfma_f32_16x16x32_f16(fah[ti], fbh[tj], accA[ti][tj], 0, 0, 0);
                accB[ti][tj] = __builtin_amdgcn_mfma_f32_16x16x32_f16(fah[ti], fbl[tj], accB[ti][tj], 0, 0, 0);
                accB[ti][tj] = __builtin_amdgcn_mfma_f32_16x16x32_f16(fal[ti], fbh[tj], accB[ti][tj], 0, 0, 0);
            }

        // late A stage: split tile it+1 (vaN) -> buf[nxt]
        if (it + 1 < 64) {
            U c0h, c0l, c1h, c1l;
#pragma unroll
            for (int j = 0; j < 8; ++j) split_f32(vaN[j],     c0h.hf[j], c0l.hf[j]);
#pragma unroll
            for (int j = 0; j < 8; ++j) split_f32(vaN[8 + j], c1h.hf[j], c1l.hf[j]);
            *(int4*)&Ah[nxt][2*h  ][lr][0] = c0h.v;
            *(int4*)&Ah[nxt][2*h+1][lr][0] = c1h.v;
            *(int4*)&Al[nxt][2*h  ][lr][0] = c0l.v;
            *(int4*)&Al[nxt][2*h+1][lr][0] = c1l.v;
        }
        if (it + 2 < 64)      { BARRIER_VM(4); }  // A(it+2) rides through
        else if (it + 1 < 64) { BARRIER_VM(0); }  // tail: drain everything
        // it == 63: no barrier, fall to epilogue
    };

    for (int it = 0; it < 64; it += 2) {
        body(it,     va0, va1, 0);
        body(it + 1, va1, va0, 1);
    }

#pragma unroll
    for (int tj = 0; tj < 4; ++tj) {
        const int o = bn*128 + nw*64 + tj*16 + l15;
        const float alpha = ab[o], beta = ab[256 + o];
#pragma unroll
        for (int ti = 0; ti < 4; ++ti) {
            const int m0 = bm*128 + mw*64 + ti*16 + quad*4;
#pragma unroll
            for (int r = 0; r < 4; ++r) {
                float c = accA[ti][tj][r] + accB[ti][tj][r] * (1.0f/2048.0f);
                float z = c * alpha + beta;
                _Float16 zh, zl;
                split_f32(z, zh, zl);
                const size_t off = (size_t)(m0 + r) * 256 + o;
                z1h[off] = zh;
                z1l[off] = zl;
            }
        }
    }
}

// ---------------------------------------------------------------------------
// K2: conv2 + bn2, fp16 2-limb MFMA GEMM. K=768 (dt*256+c), halo zero-fill.
// Same counted-vmcnt structure. Halo handled by clamped-address load + select
// (deterministic VMEM count per iter — required for manual vmcnt; no OOB).
// ---------------------------------------------------------------------------
__global__ __launch_bounds__(256, 2) void conv2_mfma(
    const _Float16* __restrict__ z1h, const _Float16* __restrict__ z1l,
    const _Float16* __restrict__ w2h, const _Float16* __restrict__ w2l,
    const float* __restrict__ ab, float* __restrict__ z2)
{
    __shared__ _Float16 Ah[2][4][128][8];
    __shared__ _Float16 Al[2][4][128][8];
    __shared__ _Float16 Bh[2][4][128][8];
    __shared__ _Float16 Bl[2][4][128][8];

    const int tid = threadIdx.x;
    const int bm = blockIdx.x, bn = blockIdx.y;
    const int lr = tid & 127;
    const int h  = tid >> 7;

    const int am = bm * 128 + lr;
    const int an = am / 63, at = am - an * 63;
    const _Float16* abase_h = z1h + (size_t)an * 16128;
    const _Float16* abase_l = z1l + (size_t)an * 16128;

    const int lane = tid & 63;
    const int wv   = tid >> 6;
    const int mw   = wv & 1, nw = wv >> 1;
    const int quad = lane >> 4;
    const int l15  = lane & 15;

    const int q0 = wv >> 1;
    const int rh = (wv & 1) * 64;
    const _Float16* bh_g = w2h + (size_t)(bn * 128 + rh + lane) * 768;
    const _Float16* bl_g = w2l + (size_t)(bn * 128 + rh + lane) * 768;

    floatx4 accA[4][4] = {};
    floatx4 accB[4][4] = {};

    const int4 z4 = {0, 0, 0, 0};
    int4 wA0[4], wA1[4];    // A prefetch depth 2: {a0h,a1h,a0l,a1l}
    bool v0, v1;            // validity for the selects

    auto issueA = [&](int it, int4 (&w)[4], bool& valid) {
        const int kap0 = it * 32;
        const int dt   = kap0 >> 8;
        const int c0   = kap0 & 255;
        const int trow = at + dt - 1;
        valid = (trow >= 0) && (trow < 63);
        const int trc  = trow < 0 ? 0 : (trow > 62 ? 62 : trow);   // clamped: always in-bounds
        const _Float16* aph = abase_h + trc * 256 + c0 + h * 16;
        const _Float16* apl = abase_l + trc * 256 + c0 + h * 16;
        w[0] = *(const int4*)(aph);
        w[1] = *(const int4*)(aph + 8);
        w[2] = *(const int4*)(apl);
        w[3] = *(const int4*)(apl + 8);
    };

    // ---- prologue ----
    {
        lds_dma16(bh_g + q0 * 8,       &Bh[0][q0    ][rh][0]);
        lds_dma16(bh_g + (q0 + 2) * 8, &Bh[0][q0 + 2][rh][0]);
        lds_dma16(bl_g + q0 * 8,       &Bl[0][q0    ][rh][0]);
        lds_dma16(bl_g + (q0 + 2) * 8, &Bl[0][q0 + 2][rh][0]);
        __builtin_amdgcn_sched_barrier(0);
        issueA(0, wA0, v0);
        issueA(1, wA1, v1);
        *(int4*)&Ah[0][2*h  ][lr][0] = v0 ? wA0[0] : z4;
        *(int4*)&Ah[0][2*h+1][lr][0] = v0 ? wA0[1] : z4;
        *(int4*)&Al[0][2*h  ][lr][0] = v0 ? wA0[2] : z4;
        *(int4*)&Al[0][2*h+1][lr][0] = v0 ? wA0[3] : z4;
        BARRIER_VM(4);
    }

    auto body = [&](int it, int4 (&wC)[4], bool& vC, int4 (&wN)[4], bool& vN, int cur) {
        const int nxt = cur ^ 1;
        if (it + 1 < 24) {
            const int ko = (it + 1) * 32;
            lds_dma16(bh_g + ko + q0 * 8,       &Bh[nxt][q0    ][rh][0]);
            lds_dma16(bh_g + ko + (q0 + 2) * 8, &Bh[nxt][q0 + 2][rh][0]);
            lds_dma16(bl_g + ko + q0 * 8,       &Bl[nxt][q0    ][rh][0]);
            lds_dma16(bl_g + ko + (q0 + 2) * 8, &Bl[nxt][q0 + 2][rh][0]);
        }
        __builtin_amdgcn_sched_barrier(0);
        if (it + 2 < 24) issueA(it + 2, wC, vC);
        __builtin_amdgcn_sched_barrier(0);

        half8 fah[4], fal[4], fbh[4], fbl[4];
#pragma unroll
        for (int t = 0; t < 4; ++t) {
            fah[t] = *(const half8*)&Ah[cur][quad][mw*64 + t*16 + l15][0];
            fal[t] = *(const half8*)&Al[cur][quad][mw*64 + t*16 + l15][0];
            fbh[t] = *(const half8*)&Bh[cur][quad][nw*64 + t*16 + l15][0];
            fbl[t] = *(const half8*)&Bl[cur][quad][nw*64 + t*16 + l15][0];
        }
#pragma unroll
        for (int ti = 0; ti < 4; ++ti)
#pragma unroll
            for (int tj = 0; tj < 4; ++tj) {
                accA[ti][tj] = __builtin_amdgcn_mfma_f32_16x16x32_f16(fah[ti], fbh[tj], accA[ti][tj], 0, 0, 0);
                accB[ti][tj] = __builtin_amdgcn_mfma_f32_16x16x32_f16(fah[ti], fbl[tj], accB[ti][tj], 0, 0, 0);
                accB[ti][tj] = __builtin_amdgcn_mfma_f32_16x16x32_f16(fal[ti], fbh[tj], accB[ti][tj], 0, 0, 0);
            }

        if (it + 1 < 24) {
            *(int4*)&Ah[nxt][2*h  ][lr][0] = vN ? wN[0] : z4;
            *(int4*)&Ah[nxt][2*h+1][lr][0] = vN ? wN[1] : z4;
            *(int4*)&Al[nxt][2*h  ][lr][0] = vN ? wN[2] : z4;
            *(int4*)&Al[nxt][2*h+1][lr][0] = vN ? wN[3] : z4;
        }
        if (it + 2 < 24)      { BARRIER_VM(4); }
        else if (it + 1 < 24) { BARRIER_VM(0); }
    };

    for (int it = 0; it < 24; it += 2) {
        body(it,     wA0, v0, wA1, v1, 0);
        body(it + 1, wA1, v1, wA0, v0, 1);
    }

#pragma unroll
    for (int tj = 0; tj < 4; ++tj) {
        const int o = bn*128 + nw*64 + tj*16 + l15;
        const float alpha = ab[o], beta = ab[256 + o];
#pragma unroll
        for (int ti = 0; ti < 4; ++ti) {
            const int m0 = bm*128 + mw*64 + ti*16 + quad*4;
#pragma unroll
            for (int r = 0; r < 4; ++r) {
                float c = accA[ti][tj][r] + accB[ti][tj][r] * (1.0f/2048.0f);
                z2[(size_t)(m0 + r) * 256 + o] = c * alpha + beta;
            }
        }
    }
}

// ---------------------------------------------------------------------------
// K3a: cuba1 — z2 [n][t][c] -> binary spikes s1 (fp16 {0,1}) in [n][t][c]
// Loads batched 9-deep so HBM latency amortizes over the serial scan.
// ---------------------------------------------------------------------------
__global__ __launch_bounds__(256) void cuba1_kernel(
    const float* __restrict__ z2, _Float16* __restrict__ s1)
{
    const int n   = blockIdx.x;
    const int tid = threadIdx.x;
    const float* zrow = z2 + (size_t)n * 16128 + tid;
    _Float16*    srow = s1 + (size_t)n * 16128 + tid;
    float cur = 0.f, vol = 0.f;
    for (int tb = 0; tb < 63; tb += 9) {
        float xv[9];
#pragma unroll
        for (int j = 0; j < 9; ++j)
            xv[j] = zrow[(size_t)(tb + j) * 256];
#pragma unroll
        for (int j = 0; j < 9; ++j) {
            cur = 0.1f * cur + xv[j];
            vol = 0.1f * vol + cur;
            bool sp = (vol - 0.3f) >= 0.f;
            srow[(size_t)(tb + j) * 256] = sp ? (_Float16)1.0f : (_Float16)0.0f;
            if (sp) vol = 0.f;
        }
    }
}

// ---------------------------------------------------------------------------
// K3b: dense1 via MFMA. M=32256, K=256, N=256. A binary fp16, B 2-limb.
// Full-DMA, TRIPLE-buffered, counted vmcnt(6): DMA pipeline is 2 tiles deep.
// ---------------------------------------------------------------------------
__global__ __launch_bounds__(256, 2) void dense1_mfma(
    const _Float16* __restrict__ s1,
    const _Float16* __restrict__ wdh, const _Float16* __restrict__ wdl,
    float* __restrict__ y1)
{
    __shared__ _Float16 As[3][4][128][8];
    __shared__ _Float16 Bh[3][4][128][8];
    __shared__ _Float16 Bl[3][4][128][8];

    const int tid = threadIdx.x;
    const int bm = blockIdx.x, bn = blockIdx.y;

    const int lane = tid & 63;
    const int wv   = tid >> 6;
    const int mw   = wv & 1, nw = wv >> 1;
    const int quad = lane >> 4;
    const int l15  = lane & 15;

    const int q0 = wv >> 1;
    const int rh = (wv & 1) * 64;
    const _Float16* a_g  = s1  + (size_t)(bm * 128 + rh + lane) * 256;
    const _Float16* bh_g = wdh + (size_t)(bn * 128 + rh + lane) * 256;
    const _Float16* bl_g = wdl + (size_t)(bn * 128 + rh + lane) * 256;

    floatx4 accA[4][4] = {};
    floatx4 accB[4][4] = {};

    auto stage = [&](int it, int b) {
        const int ko = it * 32;
        lds_dma16(a_g  + ko + q0 * 8,       &As[b][q0    ][rh][0]);
        lds_dma16(a_g  + ko + (q0 + 2) * 8, &As[b][q0 + 2][rh][0]);
        lds_dma16(bh_g + ko + q0 * 8,       &Bh[b][q0    ][rh][0]);
        lds_dma16(bh_g + ko + (q0 + 2) * 8, &Bh[b][q0 + 2][rh][0]);
        lds_dma16(bl_g + ko + q0 * 8,       &Bl[b][q0    ][rh][0]);
        lds_dma16(bl_g + ko + (q0 + 2) * 8, &Bl[b][q0 + 2][rh][0]);
    };

    // prologue: tiles 0 and 1 in flight; tile 0 complete after barrier
    stage(0, 0);
    stage(1, 1);
    BARRIER_VM(6);

#pragma unroll
    for (int it = 0; it < 8; ++it) {
        const int b = it % 3;
        if (it + 2 < 8) stage(it + 2, (it + 2) % 3);

        half8 fa[4], fbh[4], fbl[4];
#pragma unroll
        for (int t = 0; t < 4; ++t) {
            fa[t]  = *(const half8*)&As[b][quad][mw*64 + t*16 + l15][0];
            fbh[t] = *(const half8*)&Bh[b][quad][nw*64 + t*16 + l15][0];
            fbl[t] = *(const half8*)&Bl[b][quad][nw*64 + t*16 + l15][0];
        }
#pragma unroll
        for (int ti = 0; ti < 4; ++ti)
#pragma unroll
            for (int tj = 0; tj < 4; ++tj) {
                accA[ti][tj] = __builtin_amdgcn_mfma_f32_16x16x32_f16(fa[ti], fbh[tj], accA[ti][tj], 0, 0, 0);
                accB[ti][tj] = __builtin_amdgcn_mfma_f32_16x16x32_f16(fa[ti], fbl[tj], accB[ti][tj], 0, 0, 0);
            }

        if (it + 2 < 8)      { BARRIER_VM(6); }   // tile it+1 done, it+2 in flight
        else if (it + 1 < 8) { BARRIER_VM(0); }   // tail drain
    }

#pragma unroll
    for (int tj = 0; tj < 4; ++tj) {
        const int o = bn*128 + nw*64 + tj*16 + l15;
#pragma unroll
        for (int ti = 0; ti < 4; ++ti) {
            const int m0 = bm*128 + mw*64 + ti*16 + quad*4;
#pragma unroll
            for (int r = 0; r < 4; ++r)
                y1[(size_t)(m0 + r) * 256 + o] =
                    accA[ti][tj][r] + accB[ti][tj][r] * (1.0f/2048.0f);
        }
    }
}

// ---------------------------------------------------------------------------
// K3c: cuba2 (per (n,o) over t) -> spike masks -> dense2 -> cuba3 -> out
// ---------------------------------------------------------------------------
__global__ __launch_bounds__(256) void snn_tail(
    const float* __restrict__ y1, const float* __restrict__ w2,
    float* __restrict__ out)
{
    __shared__ unsigned long long M2[256];
    __shared__ float Y[2 * 63];
    const int n   = blockIdx.x;
    const int tid = threadIdx.x;

    {
        const float* yrow = y1 + (size_t)n * 16128 + tid;
        float v = 0.f;
        unsigned long long mask2 = 0ull;
        for (int t = 0; t < 63; ++t) {
            float yv = yrow[(size_t)t * 256];
            v = 0.9f * v + yv;                 // cd=0 -> i = x
            if ((v - 0.1f) >= 0.f) { mask2 |= (1ull << t); v = 0.f; }
        }
        M2[tid] = mask2;
    }
    __syncthreads();

    if (tid < 126) {
        const int cls = tid / 63;
        const int t   = tid - cls * 63;
        const float* wrow = w2 + cls * 256;
        float acc = 0.f;
#pragma unroll 4
        for (int o = 0; o < 256; ++o)
            acc += ((M2[o] >> t) & 1ull) ? wrow[o] : 0.f;
        Y[cls * 63 + t] = acc;
    }
    __syncthreads();
    if (tid < 2) {
        float v = 0.f;
        float* orow = out + (size_t)n * 126 + tid * 63;
        for (int t = 0; t < 63; ++t) {
            v = 0.9f * v + Y[tid * 63 + t];
            float u = v - 0.1f;
            float s = (u >= 0.f) ? 1.f : 0.f;
            orow[t] = s;
            v = (u >= 0.f) ? 0.f : v;
        }
    }
}

// ---------------------------------------------------------------------------
extern "C" void kernel_launch(void* const* d_in, const int* in_sizes, int n_in,
                              void* d_out, int out_size, void* d_ws, size_t ws_size,
                              hipStream_t stream)
{
    const float* x    = (const float*)d_in[0];
    const float* c1w  = (const float*)d_in[1];
    const float* c1b  = (const float*)d_in[2];
    const float* g1   = (const float*)d_in[3];
    const float* b1   = (const float*)d_in[4];
    const float* m1   = (const float*)d_in[5];
    const float* v1   = (const float*)d_in[6];
    const float* c2w  = (const float*)d_in[7];
    const float* c2b  = (const float*)d_in[8];
    const float* g2   = (const float*)d_in[9];
    const float* b2   = (const float*)d_in[10];
    const float* m2   = (const float*)d_in[11];
    const float* v2   = (const float*)d_in[12];
    const float* w1   = (const float*)d_in[13];
    const float* w2   = (const float*)d_in[14];
    float* out = (float*)d_out;

    float* ws = (float*)d_ws;
    // region A: z1 limbs during conv; reused as y1 (fp32) after conv2
    float*    zA  = ws;                               // 8,257,536 f
    _Float16* z1h = (_Float16*)zA;
    _Float16* z1l = (_Float16*)(zA + 4128768);
    float*    y1  = zA;
    float*    z2  = zA + 8257536;                     // 8,257,536 f
    _Float16* s1  = (_Float16*)(z2 + 8257536);        // 4,128,768 f
    float*    wsp = z2 + 8257536 + 4128768;
    _Float16* w1h = (_Float16*)wsp;                   // 262,144 f
    _Float16* w1l = (_Float16*)(wsp + 262144);        // 262,144 f
    _Float16* w2h = (_Float16*)(wsp + 2*262144);                    //  98,304 f
    _Float16* w2l = (_Float16*)(wsp + 2*262144 + 98304);            //  98,304 f
    _Float16* wdh = (_Float16*)(wsp + 2*262144 + 2*98304);          //  32,768 f
    _Float16* wdl = (_Float16*)(wsp + 2*262144 + 2*98304 + 32768);  //  32,768 f
    float*    ab1 = wsp + 2*262144 + 2*98304 + 2*32768;
    float*    ab2 = ab1 + 512;

    prep_kernel<<<256, 256, 0, stream>>>(c1w, c1b, g1, b1, m1, v1,
                                         c2w, c2b, g2, b2, m2, v2,
                                         w1, w1h, w1l, w2h, w2l, wdh, wdl,
                                         ab1, ab2);
    conv1_mfma<<<dim3(252, 2), 256, 0, stream>>>(x, w1h, w1l, ab1, z1h, z1l);
    conv2_mfma<<<dim3(252, 2), 256, 0, stream>>>(z1h, z1l, w2h, w2l, ab2, z2);
    cuba1_kernel<<<512, 256, 0, stream>>>(z2, s1);
    dense1_mfma<<<dim3(252, 2), 256, 0, stream>>>(s1, wdh, wdl, y1);
    snn_tail<<<512, 256, 0, stream>>>(y1, w2, out);
}

// Round 4
// 446.732 us; speedup vs baseline: 1.0723x; 1.0723x over previous
//
#include <hip/hip_runtime.h>
#include <cstdint>
#include <cstddef>

// x: [512][64][1024], conv1: K=32 S=16 -> T=63, Cout=256
// z1 stored PADDED: [n][t'][c], t' = t+1, rows t'=0 and t'=64 are zero (halo).
// fp16 2-limb: v ~= hi + lo*(1/2048), hi=fp16(v), lo=fp16((v-hi)*2048)

typedef _Float16 half8 __attribute__((ext_vector_type(8)));
typedef float floatx4 __attribute__((ext_vector_type(4)));

__device__ __forceinline__ void split_f32(float v, _Float16& hi, _Float16& lo) {
    _Float16 h = (_Float16)v;
    hi = h;
    lo = (_Float16)((v - (float)h) * 2048.0f);
}

// global -> LDS direct DMA, 16B per lane (wave-uniform LDS base + lane*16)
typedef const __attribute__((address_space(1))) unsigned int* gas_ptr;
typedef __attribute__((address_space(3))) unsigned int* las_ptr;
__device__ __forceinline__ void lds_dma16(const void* g, void* l) {
    __builtin_amdgcn_global_load_lds((gas_ptr)g, (las_ptr)l, 16, 0, 0);
}

// ---------------------------------------------------------------------------
// K0: prep — BN fold, fp16 limb splits, z1p halo-row zeroing
// ---------------------------------------------------------------------------
__global__ __launch_bounds__(256) void prep_kernel(
    const float* __restrict__ c1w, const float* __restrict__ c1b,
    const float* __restrict__ g1,  const float* __restrict__ b1,
    const float* __restrict__ m1,  const float* __restrict__ v1,
    const float* __restrict__ c2w, const float* __restrict__ c2b,
    const float* __restrict__ g2,  const float* __restrict__ b2,
    const float* __restrict__ m2,  const float* __restrict__ v2,
    const float* __restrict__ w1,
    _Float16* __restrict__ w1h, _Float16* __restrict__ w1l,
    _Float16* __restrict__ w2h, _Float16* __restrict__ w2l,
    _Float16* __restrict__ wdh, _Float16* __restrict__ wdl,
    _Float16* __restrict__ z1ph, _Float16* __restrict__ z1pl,
    float* __restrict__ ab1, float* __restrict__ ab2)
{
    const int id = blockIdx.x * 256 + threadIdx.x;   // 65536 total
    if (id < 256) {
        float a1 = g1[id] / sqrtf(v1[id] + 1e-5f);
        ab1[id]       = a1;
        ab1[256 + id] = (c1b[id] - m1[id]) * a1 + b1[id];
        float a2 = g2[id] / sqrtf(v2[id] + 1e-5f);
        ab2[id]       = a2;
        ab2[256 + id] = (c2b[id] - m2[id]) * a2 + b2[id];
    }
    // zero z1p halo rows (t'=0 and t'=64) for all n: 128 threads per n, 4 halfs each
    {
        const int n  = id >> 7;           // 0..511
        const int j  = id & 127;          // 0..127
        const int row = (j < 64) ? 0 : 64;
        const int c0  = (j & 63) * 4;
        const size_t off = ((size_t)n * 65 + row) * 256 + c0;
        short4 zz = {0, 0, 0, 0};
        *(short4*)&z1ph[off] = zz;
        *(short4*)&z1pl[off] = zz;
    }
    // dense1 weights: w1[o][c] row-major already == B-row layout [o][k=c]
    split_f32(w1[id], wdh[id], wdl[id]);
    // conv1_w limbs: [o][2048] direct layout
    for (int idx = id; idx < 256 * 2048; idx += 65536)
        split_f32(c1w[idx], w1h[idx], w1l[idx]);
    // conv2_w limbs transposed to [o][dt*256+c]
    for (int idx = id; idx < 256 * 768; idx += 65536) {
        const int o  = idx / 768;
        const int r  = idx - o * 768;
        const int dt = r >> 8;
        const int c  = r & 255;
        split_f32(c2w[o * 768 + c * 3 + dt], w2h[idx], w2l[idx]);
    }
}

// ---------------------------------------------------------------------------
// K1: conv1 + bn1, fp16 2-limb MFMA GEMM. M=32256, K=2048 (c*32+k), N=256.
// R0 structure verbatim (proven best); epilogue writes PADDED z1p rows t+1.
// ---------------------------------------------------------------------------
__global__ __launch_bounds__(256, 2) void conv1_mfma(
    const float* __restrict__ x,
    const _Float16* __restrict__ w1h, const _Float16* __restrict__ w1l,
    const float* __restrict__ ab,
    _Float16* __restrict__ z1ph, _Float16* __restrict__ z1pl)
{
    __shared__ _Float16 Ah[4][128][8];   // [k-quad][m][8] fragment-major
    __shared__ _Float16 Al[4][128][8];
    __shared__ _Float16 Bh[4][128][8];
    __shared__ _Float16 Bl[4][128][8];

    const int tid = threadIdx.x;
    const int bm = blockIdx.x, bn = blockIdx.y;
    const int lr = tid & 127;
    const int h  = tid >> 7;

    const int am = bm * 128 + lr;
    const int an = am / 63, at = am - an * 63;
    const float*    arow  = x   + (size_t)an * 65536 + at * 16 + h * 16;
    const _Float16* bhrow = w1h + (size_t)(bn * 128 + lr) * 2048 + h * 16;
    const _Float16* blrow = w1l + (size_t)(bn * 128 + lr) * 2048 + h * 16;

    const int lane = tid & 63;
    const int wv   = tid >> 6;
    const int mw   = wv & 1, nw = wv >> 1;
    const int quad = lane >> 4;
    const int l15  = lane & 15;

    floatx4 accA[4][4] = {};
    floatx4 accB[4][4] = {};

    for (int it = 0; it < 64; ++it) {
        const float* ap = arow + it * 1024;
        float va[16];
        *(float4*)&va[0]  = *(const float4*)(ap);
        *(float4*)&va[4]  = *(const float4*)(ap + 4);
        *(float4*)&va[8]  = *(const float4*)(ap + 8);
        *(float4*)&va[12] = *(const float4*)(ap + 12);
        int4 bh0 = *(const int4*)(bhrow + it * 32);
        int4 bh1 = *(const int4*)(bhrow + it * 32 + 8);
        int4 bl0 = *(const int4*)(blrow + it * 32);
        int4 bl1 = *(const int4*)(blrow + it * 32 + 8);

        union U { _Float16 hf[8]; int4 v; };
        U c0h, c0l, c1h, c1l;
#pragma unroll
        for (int j = 0; j < 8; ++j) split_f32(va[j],     c0h.hf[j], c0l.hf[j]);
#pragma unroll
        for (int j = 0; j < 8; ++j) split_f32(va[8 + j], c1h.hf[j], c1l.hf[j]);

        __syncthreads();
        *(int4*)&Ah[2*h  ][lr][0] = c0h.v;
        *(int4*)&Ah[2*h+1][lr][0] = c1h.v;
        *(int4*)&Al[2*h  ][lr][0] = c0l.v;
        *(int4*)&Al[2*h+1][lr][0] = c1l.v;
        *(int4*)&Bh[2*h  ][lr][0] = bh0;
        *(int4*)&Bh[2*h+1][lr][0] = bh1;
        *(int4*)&Bl[2*h  ][lr][0] = bl0;
        *(int4*)&Bl[2*h+1][lr][0] = bl1;
        __syncthreads();

        half8 fah[4], fal[4], fbh[4], fbl[4];
#pragma unroll
        for (int t = 0; t < 4; ++t) {
            fah[t] = *(const half8*)&Ah[quad][mw*64 + t*16 + l15][0];
            fal[t] = *(const half8*)&Al[quad][mw*64 + t*16 + l15][0];
            fbh[t] = *(const half8*)&Bh[quad][nw*64 + t*16 + l15][0];
            fbl[t] = *(const half8*)&Bl[quad][nw*64 + t*16 + l15][0];
        }
#pragma unroll
        for (int ti = 0; ti < 4; ++ti)
#pragma unroll
            for (int tj = 0; tj < 4; ++tj) {
                accA[ti][tj] = __builtin_amdgcn_mfma_f32_16x16x32_f16(fah[ti], fbh[tj], accA[ti][tj], 0, 0, 0);
                accB[ti][tj] = __builtin_amdgcn_mfma_f32_16x16x32_f16(fah[ti], fbl[tj], accB[ti][tj], 0, 0, 0);
                accB[ti][tj] = __builtin_amdgcn_mfma_f32_16x16x32_f16(fal[ti], fbh[tj], accB[ti][tj], 0, 0, 0);
            }
    }

#pragma unroll
    for (int tj = 0; tj < 4; ++tj) {
        const int o = bn*128 + nw*64 + tj*16 + l15;
        const float alpha = ab[o], beta = ab[256 + o];
#pragma unroll
        for (int ti = 0; ti < 4; ++ti) {
            const int m0 = bm*128 + mw*64 + ti*16 + quad*4;
#pragma unroll
            for (int r = 0; r < 4; ++r) {
                float c = accA[ti][tj][r] + accB[ti][tj][r] * (1.0f/2048.0f);
                float z = c * alpha + beta;
                _Float16 zh, zl;
                split_f32(z, zh, zl);
                const int m  = m0 + r;
                const int a2 = m / 63;
                const int t2 = m - a2 * 63;
                const size_t off = ((size_t)a2 * 65 + t2 + 1) * 256 + o;  // padded row t+1
                z1ph[off] = zh;
                z1pl[off] = zl;
            }
        }
    }
}

// ---------------------------------------------------------------------------
// K2: conv2 + bn2, ALL-DMA fp16 2-limb MFMA GEMM. K=768, BK=64, 12 iters.
// Padded z1p makes every A address valid (halo rows are zeros) and exactly
// linear in k: off = an*16640 + at*256 + k. Zero in-loop VALU, zero staging
// registers — all four operand tiles via global_load_lds.
// ---------------------------------------------------------------------------
__global__ __launch_bounds__(256, 2) void conv2_mfma(
    const _Float16* __restrict__ z1ph, const _Float16* __restrict__ z1pl,
    const _Float16* __restrict__ w2h, const _Float16* __restrict__ w2l,
    const float* __restrict__ ab, float* __restrict__ z2)
{
    __shared__ _Float16 Ah[8][128][8];   // 16 KB each, 64 KB total
    __shared__ _Float16 Al[8][128][8];
    __shared__ _Float16 Bh[8][128][8];
    __shared__ _Float16 Bl[8][128][8];

    const int tid = threadIdx.x;
    const int bm = blockIdx.x, bn = blockIdx.y;
    const int lr = tid & 127;
    const int h  = tid >> 7;

    const int am = bm * 128 + lr;
    const int an = am / 63, at = am - an * 63;
    const _Float16* pAh = z1ph + (size_t)an * 16640 + at * 256 + h * 8;
    const _Float16* pAl = z1pl + (size_t)an * 16640 + at * 256 + h * 8;
    const _Float16* pBh = w2h + (size_t)(bn * 128 + lr) * 768 + h * 8;
    const _Float16* pBl = w2l + (size_t)(bn * 128 + lr) * 768 + h * 8;

    const int lane = tid & 63;
    const int wv   = tid >> 6;
    const int mw   = wv & 1, nw = wv >> 1;
    const int quad = lane >> 4;
    const int l15  = lane & 15;

    floatx4 accA[4][4] = {};
    floatx4 accB[4][4] = {};

    for (int it = 0; it < 12; ++it) {
        __syncthreads();                 // previous tile fully consumed
#pragma unroll
        for (int q = 0; q < 4; ++q) {    // slot (kq = q*2+h, row = lr)
            lds_dma16(pAh + q * 16, &Ah[q*2 + h][lr][0]);
            lds_dma16(pAl + q * 16, &Al[q*2 + h][lr][0]);
            lds_dma16(pBh + q * 16, &Bh[q*2 + h][lr][0]);
            lds_dma16(pBl + q * 16, &Bl[q*2 + h][lr][0]);
        }
        __syncthreads();                 // implicit vmcnt(0): DMA landed

#pragma unroll
        for (int ks = 0; ks < 2; ++ks) {
            half8 fah[4], fal[4], fbh[4], fbl[4];
#pragma unroll
            for (int t = 0; t < 4; ++t) {
                fah[t] = *(const half8*)&Ah[ks*4 + quad][mw*64 + t*16 + l15][0];
                fal[t] = *(const half8*)&Al[ks*4 + quad][mw*64 + t*16 + l15][0];
                fbh[t] = *(const half8*)&Bh[ks*4 + quad][nw*64 + t*16 + l15][0];
                fbl[t] = *(const half8*)&Bl[ks*4 + quad][nw*64 + t*16 + l15][0];
            }
#pragma unroll
            for (int ti = 0; ti < 4; ++ti)
#pragma unroll
                for (int tj = 0; tj < 4; ++tj) {
                    accA[ti][tj] = __builtin_amdgcn_mfma_f32_16x16x32_f16(fah[ti], fbh[tj], accA[ti][tj], 0, 0, 0);
                    accB[ti][tj] = __builtin_amdgcn_mfma_f32_16x16x32_f16(fah[ti], fbl[tj], accB[ti][tj], 0, 0, 0);
                    accB[ti][tj] = __builtin_amdgcn_mfma_f32_16x16x32_f16(fal[ti], fbh[tj], accB[ti][tj], 0, 0, 0);
                }
        }
        pAh += 64; pAl += 64; pBh += 64; pBl += 64;
    }

#pragma unroll
    for (int tj = 0; tj < 4; ++tj) {
        const int o = bn*128 + nw*64 + tj*16 + l15;
        const float alpha = ab[o], beta = ab[256 + o];
#pragma unroll
        for (int ti = 0; ti < 4; ++ti) {
            const int m0 = bm*128 + mw*64 + ti*16 + quad*4;
#pragma unroll
            for (int r = 0; r < 4; ++r) {
                float c = accA[ti][tj][r] + accB[ti][tj][r] * (1.0f/2048.0f);
                z2[(size_t)(m0 + r) * 256 + o] = c * alpha + beta;
            }
        }
    }
}

// ---------------------------------------------------------------------------
// K3a: cuba1 — z2 [n][t][c] -> binary spikes s1 (fp16 {0,1}) in [n][t][c]
// ---------------------------------------------------------------------------
__global__ __launch_bounds__(256) void cuba1_kernel(
    const float* __restrict__ z2, _Float16* __restrict__ s1)
{
    const int n   = blockIdx.x;
    const int tid = threadIdx.x;
    const float* zrow = z2 + (size_t)n * 16128 + tid;
    _Float16*    srow = s1 + (size_t)n * 16128 + tid;
    float cur = 0.f, vol = 0.f;
    for (int tb = 0; tb < 63; tb += 9) {
        float xv[9];
#pragma unroll
        for (int j = 0; j < 9; ++j)
            xv[j] = zrow[(size_t)(tb + j) * 256];
#pragma unroll
        for (int j = 0; j < 9; ++j) {
            cur = 0.1f * cur + xv[j];
            vol = 0.1f * vol + cur;
            bool sp = (vol - 0.3f) >= 0.f;
            srow[(size_t)(tb + j) * 256] = sp ? (_Float16)1.0f : (_Float16)0.0f;
            if (sp) vol = 0.f;
        }
    }
}

// ---------------------------------------------------------------------------
// K3b: dense1, ALL-DMA MFMA. M=32256, K=256 (BK=64, 4 iters), N=256.
// A binary fp16 (1 limb), B 2-limb. Single-buffer, 2 barriers/iter.
// ---------------------------------------------------------------------------
__global__ __launch_bounds__(256, 2) void dense1_mfma(
    const _Float16* __restrict__ s1,
    const _Float16* __restrict__ wdh, const _Float16* __restrict__ wdl,
    float* __restrict__ y1)
{
    __shared__ _Float16 As[8][128][8];
    __shared__ _Float16 Bh[8][128][8];
    __shared__ _Float16 Bl[8][128][8];

    const int tid = threadIdx.x;
    const int bm = blockIdx.x, bn = blockIdx.y;
    const int lr = tid & 127;
    const int h  = tid >> 7;

    const _Float16* pA  = s1  + (size_t)(bm * 128 + lr) * 256 + h * 8;
    const _Float16* pBh = wdh + (size_t)(bn * 128 + lr) * 256 + h * 8;
    const _Float16* pBl = wdl + (size_t)(bn * 128 + lr) * 256 + h * 8;

    const int lane = tid & 63;
    const int wv   = tid >> 6;
    const int mw   = wv & 1, nw = wv >> 1;
    const int quad = lane >> 4;
    const int l15  = lane & 15;

    floatx4 accA[4][4] = {};
    floatx4 accB[4][4] = {};

    for (int it = 0; it < 4; ++it) {
        __syncthreads();
#pragma unroll
        for (int q = 0; q < 4; ++q) {
            lds_dma16(pA  + q * 16, &As[q*2 + h][lr][0]);
            lds_dma16(pBh + q * 16, &Bh[q*2 + h][lr][0]);
            lds_dma16(pBl + q * 16, &Bl[q*2 + h][lr][0]);
        }
        __syncthreads();

#pragma unroll
        for (int ks = 0; ks < 2; ++ks) {
            half8 fa[4], fbh[4], fbl[4];
#pragma unroll
            for (int t = 0; t < 4; ++t) {
                fa[t]  = *(const half8*)&As[ks*4 + quad][mw*64 + t*16 + l15][0];
                fbh[t] = *(const half8*)&Bh[ks*4 + quad][nw*64 + t*16 + l15][0];
                fbl[t] = *(const half8*)&Bl[ks*4 + quad][nw*64 + t*16 + l15][0];
            }
#pragma unroll
            for (int ti = 0; ti < 4; ++ti)
#pragma unroll
                for (int tj = 0; tj < 4; ++tj) {
                    accA[ti][tj] = __builtin_amdgcn_mfma_f32_16x16x32_f16(fa[ti], fbh[tj], accA[ti][tj], 0, 0, 0);
                    accB[ti][tj] = __builtin_amdgcn_mfma_f32_16x16x32_f16(fa[ti], fbl[tj], accB[ti][tj], 0, 0, 0);
                }
        }
        pA += 64; pBh += 64; pBl += 64;
    }

#pragma unroll
    for (int tj = 0; tj < 4; ++tj) {
        const int o = bn*128 + nw*64 + tj*16 + l15;
#pragma unroll
        for (int ti = 0; ti < 4; ++ti) {
            const int m0 = bm*128 + mw*64 + ti*16 + quad*4;
#pragma unroll
            for (int r = 0; r < 4; ++r)
                y1[(size_t)(m0 + r) * 256 + o] =
                    accA[ti][tj][r] + accB[ti][tj][r] * (1.0f/2048.0f);
        }
    }
}

// ---------------------------------------------------------------------------
// K3c: cuba2 (per (n,o) over t) -> spike masks -> dense2 -> cuba3 -> out
// ---------------------------------------------------------------------------
__global__ __launch_bounds__(256) void snn_tail(
    const float* __restrict__ y1, const float* __restrict__ w2,
    float* __restrict__ out)
{
    __shared__ unsigned long long M2[256];
    __shared__ float Y[2 * 63];
    const int n   = blockIdx.x;
    const int tid = threadIdx.x;

    {
        const float* yrow = y1 + (size_t)n * 16128 + tid;
        float v = 0.f;
        unsigned long long mask2 = 0ull;
        for (int t = 0; t < 63; ++t) {
            float yv = yrow[(size_t)t * 256];
            v = 0.9f * v + yv;                 // cd=0 -> i = x
            if ((v - 0.1f) >= 0.f) { mask2 |= (1ull << t); v = 0.f; }
        }
        M2[tid] = mask2;
    }
    __syncthreads();

    if (tid < 126) {
        const int cls = tid / 63;
        const int t   = tid - cls * 63;
        const float* wrow = w2 + cls * 256;
        float acc = 0.f;
#pragma unroll 4
        for (int o = 0; o < 256; ++o)
            acc += ((M2[o] >> t) & 1ull) ? wrow[o] : 0.f;
        Y[cls * 63 + t] = acc;
    }
    __syncthreads();
    if (tid < 2) {
        float v = 0.f;
        float* orow = out + (size_t)n * 126 + tid * 63;
        for (int t = 0; t < 63; ++t) {
            v = 0.9f * v + Y[tid * 63 + t];
            float u = v - 0.1f;
            float s = (u >= 0.f) ? 1.f : 0.f;
            orow[t] = s;
            v = (u >= 0.f) ? 0.f : v;
        }
    }
}

// ---------------------------------------------------------------------------
extern "C" void kernel_launch(void* const* d_in, const int* in_sizes, int n_in,
                              void* d_out, int out_size, void* d_ws, size_t ws_size,
                              hipStream_t stream)
{
    const float* x    = (const float*)d_in[0];
    const float* c1w  = (const float*)d_in[1];
    const float* c1b  = (const float*)d_in[2];
    const float* g1   = (const float*)d_in[3];
    const float* b1   = (const float*)d_in[4];
    const float* m1   = (const float*)d_in[5];
    const float* v1   = (const float*)d_in[6];
    const float* c2w  = (const float*)d_in[7];
    const float* c2b  = (const float*)d_in[8];
    const float* g2   = (const float*)d_in[9];
    const float* b2   = (const float*)d_in[10];
    const float* m2   = (const float*)d_in[11];
    const float* v2   = (const float*)d_in[12];
    const float* w1   = (const float*)d_in[13];
    const float* w2   = (const float*)d_in[14];
    float* out = (float*)d_out;

    float* ws = (float*)d_ws;
    // layout (float units):
    //   [0, 8519680)         z1p limbs (padded [512][65][256] fp16 x2)
    //     y1 (fp32, 8257536) aliases this region after conv2 is done
    //   [8519680, 16777216)  z2 (fp32)
    //   [16777216, 20905984) s1 (fp16 [512][63][256])
    //   [20905984, ...)      weight limbs + ab
    _Float16* z1ph = (_Float16*)ws;                       // 4,259,840 f
    _Float16* z1pl = (_Float16*)(ws + 4259840);           // 4,259,840 f
    float*    y1   = ws;                                  // alias of z1p region
    float*    z2   = ws + 8519680;                        // 8,257,536 f
    _Float16* s1   = (_Float16*)(ws + 16777216);          // 4,128,768 f
    float*    wsp  = ws + 20905984;
    _Float16* w1h = (_Float16*)wsp;                                 // 262,144 f
    _Float16* w1l = (_Float16*)(wsp + 262144);                      // 262,144 f
    _Float16* w2h = (_Float16*)(wsp + 2*262144);                    //  98,304 f
    _Float16* w2l = (_Float16*)(wsp + 2*262144 + 98304);            //  98,304 f
    _Float16* wdh = (_Float16*)(wsp + 2*262144 + 2*98304);          //  32,768 f
    _Float16* wdl = (_Float16*)(wsp + 2*262144 + 2*98304 + 32768);  //  32,768 f
    float*    ab1 = wsp + 2*262144 + 2*98304 + 2*32768;
    float*    ab2 = ab1 + 512;

    prep_kernel<<<256, 256, 0, stream>>>(c1w, c1b, g1, b1, m1, v1,
                                         c2w, c2b, g2, b2, m2, v2,
                                         w1, w1h, w1l, w2h, w2l, wdh, wdl,
                                         z1ph, z1pl, ab1, ab2);
    conv1_mfma<<<dim3(252, 2), 256, 0, stream>>>(x, w1h, w1l, ab1, z1ph, z1pl);
    conv2_mfma<<<dim3(252, 2), 256, 0, stream>>>(z1ph, z1pl, w2h, w2l, ab2, z2);
    cuba1_kernel<<<512, 256, 0, stream>>>(z2, s1);
    dense1_mfma<<<dim3(252, 2), 256, 0, stream>>>(s1, wdh, wdl, y1);
    snn_tail<<<512, 256, 0, stream>>>(y1, w2, out);
}

// Round 5
// 429.798 us; speedup vs baseline: 1.1145x; 1.0394x over previous
//
#include <hip/hip_runtime.h>
#include <cstdint>
#include <cstddef>

// x: [512][64][1024], conv1: K=32 S=16 -> T=63, Cout=256
// z1 stored PADDED: [n][t'][c], t' = t+1, rows 0, 64, 65 are zero (halo).
// fp16 2-limb: v ~= hi + lo*(1/2048), hi=fp16(v), lo=fp16((v-hi)*2048)

typedef _Float16 half8 __attribute__((ext_vector_type(8)));
typedef float floatx4 __attribute__((ext_vector_type(4)));

__device__ __forceinline__ void split_f32(float v, _Float16& hi, _Float16& lo) {
    _Float16 h = (_Float16)v;
    hi = h;
    lo = (_Float16)((v - (float)h) * 2048.0f);
}

// global -> LDS direct DMA, 16B per lane (wave-uniform LDS base + lane*16)
typedef const __attribute__((address_space(1))) unsigned int* gas_ptr;
typedef __attribute__((address_space(3))) unsigned int* las_ptr;
__device__ __forceinline__ void lds_dma16(const void* g, void* l) {
    __builtin_amdgcn_global_load_lds((gas_ptr)g, (las_ptr)l, 16, 0, 0);
}

// ---------------------------------------------------------------------------
// K0: prep — BN fold, fp16 limb splits, z1p halo-row zeroing (rows 0,64,65)
// ---------------------------------------------------------------------------
__global__ __launch_bounds__(256) void prep_kernel(
    const float* __restrict__ c1w, const float* __restrict__ c1b,
    const float* __restrict__ g1,  const float* __restrict__ b1,
    const float* __restrict__ m1,  const float* __restrict__ v1,
    const float* __restrict__ c2w, const float* __restrict__ c2b,
    const float* __restrict__ g2,  const float* __restrict__ b2,
    const float* __restrict__ m2,  const float* __restrict__ v2,
    const float* __restrict__ w1,
    _Float16* __restrict__ w1h, _Float16* __restrict__ w1l,
    _Float16* __restrict__ w2h, _Float16* __restrict__ w2l,
    _Float16* __restrict__ wdh, _Float16* __restrict__ wdl,
    _Float16* __restrict__ z1ph, _Float16* __restrict__ z1pl,
    float* __restrict__ ab1, float* __restrict__ ab2)
{
    const int id = blockIdx.x * 256 + threadIdx.x;   // 65536 total
    if (id < 256) {
        float a1 = g1[id] / sqrtf(v1[id] + 1e-5f);
        ab1[id]       = a1;
        ab1[256 + id] = (c1b[id] - m1[id]) * a1 + b1[id];
        float a2 = g2[id] / sqrtf(v2[id] + 1e-5f);
        ab2[id]       = a2;
        ab2[256 + id] = (c2b[id] - m2[id]) * a2 + b2[id];
    }
    // zero z1p halo rows {0,64,65} for all n: 512 n * 3 rows * 64 short4 = 98304
    {
        short4 zz = {0, 0, 0, 0};
        for (int idx = id; idx < 98304; idx += 65536) {
            const int n = idx / 192;
            const int r = idx - n * 192;
            const int rs = r >> 6;                       // 0,1,2
            const int row = (rs == 0) ? 0 : (63 + rs);   // 0,64,65
            const int c0 = (r & 63) * 4;
            const size_t off = ((size_t)n * 66 + row) * 256 + c0;
            *(short4*)&z1ph[off] = zz;
            *(short4*)&z1pl[off] = zz;
        }
    }
    // dense1 weights: w1[o][c] row-major already == B-row layout [o][k=c]
    split_f32(w1[id], wdh[id], wdl[id]);
    // conv1_w limbs: [o][2048] direct layout
    for (int idx = id; idx < 256 * 2048; idx += 65536)
        split_f32(c1w[idx], w1h[idx], w1l[idx]);
    // conv2_w limbs transposed to [o][dt*256+c]
    for (int idx = id; idx < 256 * 768; idx += 65536) {
        const int o  = idx / 768;
        const int r  = idx - o * 768;
        const int dt = r >> 8;
        const int c  = r & 255;
        split_f32(c2w[o * 768 + c * 3 + dt], w2h[idx], w2l[idx]);
    }
}

// ---------------------------------------------------------------------------
// K1: conv1 + bn1, fp16 2-limb MFMA GEMM. M=32256, K=2048 (c*32+k), N=256.
// Proven 158-µs structure; epilogue writes PADDED z1p (stride 66) rows t+1.
// ---------------------------------------------------------------------------
__global__ __launch_bounds__(256, 2) void conv1_mfma(
    const float* __restrict__ x,
    const _Float16* __restrict__ w1h, const _Float16* __restrict__ w1l,
    const float* __restrict__ ab,
    _Float16* __restrict__ z1ph, _Float16* __restrict__ z1pl)
{
    __shared__ _Float16 Ah[4][128][8];   // [k-quad][m][8] fragment-major
    __shared__ _Float16 Al[4][128][8];
    __shared__ _Float16 Bh[4][128][8];
    __shared__ _Float16 Bl[4][128][8];

    const int tid = threadIdx.x;
    const int bm = blockIdx.x, bn = blockIdx.y;
    const int lr = tid & 127;
    const int h  = tid >> 7;

    const int am = bm * 128 + lr;
    const int an = am / 63, at = am - an * 63;
    const float*    arow  = x   + (size_t)an * 65536 + at * 16 + h * 16;
    const _Float16* bhrow = w1h + (size_t)(bn * 128 + lr) * 2048 + h * 16;
    const _Float16* blrow = w1l + (size_t)(bn * 128 + lr) * 2048 + h * 16;

    const int lane = tid & 63;
    const int wv   = tid >> 6;
    const int mw   = wv & 1, nw = wv >> 1;
    const int quad = lane >> 4;
    const int l15  = lane & 15;

    floatx4 accA[4][4] = {};
    floatx4 accB[4][4] = {};

    for (int it = 0; it < 64; ++it) {
        const float* ap = arow + it * 1024;
        float va[16];
        *(float4*)&va[0]  = *(const float4*)(ap);
        *(float4*)&va[4]  = *(const float4*)(ap + 4);
        *(float4*)&va[8]  = *(const float4*)(ap + 8);
        *(float4*)&va[12] = *(const float4*)(ap + 12);
        int4 bh0 = *(const int4*)(bhrow + it * 32);
        int4 bh1 = *(const int4*)(bhrow + it * 32 + 8);
        int4 bl0 = *(const int4*)(blrow + it * 32);
        int4 bl1 = *(const int4*)(blrow + it * 32 + 8);

        union U { _Float16 hf[8]; int4 v; };
        U c0h, c0l, c1h, c1l;
#pragma unroll
        for (int j = 0; j < 8; ++j) split_f32(va[j],     c0h.hf[j], c0l.hf[j]);
#pragma unroll
        for (int j = 0; j < 8; ++j) split_f32(va[8 + j], c1h.hf[j], c1l.hf[j]);

        __syncthreads();
        *(int4*)&Ah[2*h  ][lr][0] = c0h.v;
        *(int4*)&Ah[2*h+1][lr][0] = c1h.v;
        *(int4*)&Al[2*h  ][lr][0] = c0l.v;
        *(int4*)&Al[2*h+1][lr][0] = c1l.v;
        *(int4*)&Bh[2*h  ][lr][0] = bh0;
        *(int4*)&Bh[2*h+1][lr][0] = bh1;
        *(int4*)&Bl[2*h  ][lr][0] = bl0;
        *(int4*)&Bl[2*h+1][lr][0] = bl1;
        __syncthreads();

        half8 fah[4], fal[4], fbh[4], fbl[4];
#pragma unroll
        for (int t = 0; t < 4; ++t) {
            fah[t] = *(const half8*)&Ah[quad][mw*64 + t*16 + l15][0];
            fal[t] = *(const half8*)&Al[quad][mw*64 + t*16 + l15][0];
            fbh[t] = *(const half8*)&Bh[quad][nw*64 + t*16 + l15][0];
            fbl[t] = *(const half8*)&Bl[quad][nw*64 + t*16 + l15][0];
        }
#pragma unroll
        for (int ti = 0; ti < 4; ++ti)
#pragma unroll
            for (int tj = 0; tj < 4; ++tj) {
                accA[ti][tj] = __builtin_amdgcn_mfma_f32_16x16x32_f16(fah[ti], fbh[tj], accA[ti][tj], 0, 0, 0);
                accB[ti][tj] = __builtin_amdgcn_mfma_f32_16x16x32_f16(fah[ti], fbl[tj], accB[ti][tj], 0, 0, 0);
                accB[ti][tj] = __builtin_amdgcn_mfma_f32_16x16x32_f16(fal[ti], fbh[tj], accB[ti][tj], 0, 0, 0);
            }
    }

#pragma unroll
    for (int tj = 0; tj < 4; ++tj) {
        const int o = bn*128 + nw*64 + tj*16 + l15;
        const float alpha = ab[o], beta = ab[256 + o];
#pragma unroll
        for (int ti = 0; ti < 4; ++ti) {
            const int m0 = bm*128 + mw*64 + ti*16 + quad*4;
#pragma unroll
            for (int r = 0; r < 4; ++r) {
                float c = accA[ti][tj][r] + accB[ti][tj][r] * (1.0f/2048.0f);
                float z = c * alpha + beta;
                _Float16 zh, zl;
                split_f32(z, zh, zl);
                const int m  = m0 + r;
                const int a2 = m / 63;
                const int t2 = m - a2 * 63;
                const size_t off = ((size_t)a2 * 66 + t2 + 1) * 256 + o;  // padded row t+1
                z1ph[off] = zh;
                z1pl[off] = zl;
            }
        }
    }
}

// ---------------------------------------------------------------------------
// K2: conv2 + bn2 + cuba1 FUSED. M-block = 2 batch items x 64 t-rows (1 pad).
// GEMM K=768 all-DMA (BK=64, 12 iters); epilogue stages the fp32 tile in the
// staging LDS (exactly 64 KB) and runs the 63-step LIF scan per (n,c),
// writing binary fp16 spikes straight to s1. z2 never touches HBM.
// ---------------------------------------------------------------------------
__global__ __launch_bounds__(256, 2) void conv2_cuba_mfma(
    const _Float16* __restrict__ z1ph, const _Float16* __restrict__ z1pl,
    const _Float16* __restrict__ w2h, const _Float16* __restrict__ w2l,
    const float* __restrict__ ab, _Float16* __restrict__ s1)
{
    __shared__ _Float16 SMEM[32768];     // 64 KB: staging during K-loop, z-tile after
    _Float16 (*Ah)[128][8] = reinterpret_cast<_Float16(*)[128][8]>(SMEM);
    _Float16 (*Al)[128][8] = reinterpret_cast<_Float16(*)[128][8]>(SMEM + 8192);
    _Float16 (*Bh)[128][8] = reinterpret_cast<_Float16(*)[128][8]>(SMEM + 16384);
    _Float16 (*Bl)[128][8] = reinterpret_cast<_Float16(*)[128][8]>(SMEM + 24576);

    const int tid = threadIdx.x;
    const int bm = blockIdx.x, bn = blockIdx.y;
    const int lr = tid & 127;
    const int h  = tid >> 7;

    const int n0 = bm * 2;
    const int an = lr >> 6, at = lr & 63;           // m-row = an*64 + at (at=63: pad)
    // A addr: z1p[(n0+an)][at + dt][c]; linear in k: dt*256 + (it&3)*64 == it*64
    const _Float16* pAh = z1ph + ((size_t)(n0 + an) * 66 + at) * 256 + h * 8;
    const _Float16* pAl = z1pl + ((size_t)(n0 + an) * 66 + at) * 256 + h * 8;
    const _Float16* pBh = w2h + (size_t)(bn * 128 + lr) * 768 + h * 8;
    const _Float16* pBl = w2l + (size_t)(bn * 128 + lr) * 768 + h * 8;

    const int lane = tid & 63;
    const int wv   = tid >> 6;
    const int mw   = wv & 1, nw = wv >> 1;
    const int quad = lane >> 4;
    const int l15  = lane & 15;

    floatx4 accA[4][4] = {};
    floatx4 accB[4][4] = {};

    for (int it = 0; it < 12; ++it) {
        __syncthreads();                 // previous tile fully consumed
#pragma unroll
        for (int q = 0; q < 4; ++q) {    // slot (kq = q*2+h, row = lr)
            lds_dma16(pAh + q * 16, &Ah[q*2 + h][lr][0]);
            lds_dma16(pAl + q * 16, &Al[q*2 + h][lr][0]);
            lds_dma16(pBh + q * 16, &Bh[q*2 + h][lr][0]);
            lds_dma16(pBl + q * 16, &Bl[q*2 + h][lr][0]);
        }
        __syncthreads();                 // implicit vmcnt(0): DMA landed

#pragma unroll
        for (int ks = 0; ks < 2; ++ks) {
            half8 fah[4], fal[4], fbh[4], fbl[4];
#pragma unroll
            for (int t = 0; t < 4; ++t) {
                fah[t] = *(const half8*)&Ah[ks*4 + quad][mw*64 + t*16 + l15][0];
                fal[t] = *(const half8*)&Al[ks*4 + quad][mw*64 + t*16 + l15][0];
                fbh[t] = *(const half8*)&Bh[ks*4 + quad][nw*64 + t*16 + l15][0];
                fbl[t] = *(const half8*)&Bl[ks*4 + quad][nw*64 + t*16 + l15][0];
            }
#pragma unroll
            for (int ti = 0; ti < 4; ++ti)
#pragma unroll
                for (int tj = 0; tj < 4; ++tj) {
                    accA[ti][tj] = __builtin_amdgcn_mfma_f32_16x16x32_f16(fah[ti], fbh[tj], accA[ti][tj], 0, 0, 0);
                    accB[ti][tj] = __builtin_amdgcn_mfma_f32_16x16x32_f16(fah[ti], fbl[tj], accB[ti][tj], 0, 0, 0);
                    accB[ti][tj] = __builtin_amdgcn_mfma_f32_16x16x32_f16(fal[ti], fbh[tj], accB[ti][tj], 0, 0, 0);
                }
        }
        pAh += 64; pAl += 64; pBh += 64; pBl += 64;
    }

    // ---- fused epilogue: z tile -> LDS fp32 [128 m][128 c], then LIF scan ----
    __syncthreads();                     // all waves done reading staging
    float* zt = (float*)SMEM;            // 128*128 fp32 = 64 KB (exact fit)
#pragma unroll
    for (int tj = 0; tj < 4; ++tj) {
        const int cl = nw*64 + tj*16 + l15;
        const int o  = bn*128 + cl;
        const float alpha = ab[o], beta = ab[256 + o];
#pragma unroll
        for (int ti = 0; ti < 4; ++ti) {
            const int m0 = mw*64 + ti*16 + quad*4;
#pragma unroll
            for (int r = 0; r < 4; ++r) {
                float c = accA[ti][tj][r] + accB[ti][tj][r] * (1.0f/2048.0f);
                zt[(m0 + r) * 128 + cl] = c * alpha + beta;
            }
        }
    }
    __syncthreads();

    // cuba1: thread owns (nl, cloc); reads LDS (lanes = consecutive columns,
    // conflict-free), writes coalesced fp16 spikes.
    const int nl   = tid >> 7;
    const int cloc = tid & 127;
    const int n    = n0 + nl;
    _Float16* srow = s1 + (size_t)n * 16128 + bn*128 + cloc;
    float cur = 0.f, vol = 0.f;
    for (int t = 0; t < 63; ++t) {
        float xv = zt[(nl*64 + t) * 128 + cloc];
        cur = 0.1f * cur + xv;
        vol = 0.1f * vol + cur;
        bool sp = (vol - 0.3f) >= 0.f;
        srow[(size_t)t * 256] = sp ? (_Float16)1.0f : (_Float16)0.0f;
        if (sp) vol = 0.f;
    }
}

// ---------------------------------------------------------------------------
// K3: dense1 + cuba2 FUSED. Same 2n x 64t M-blocks. GEMM K=256 all-DMA
// (BK=64, 4 iters). Epilogue: y tile -> LDS, LIF scan -> 63-bit spike mask
// per (n,o) -> 1 MB mask buffer (replaces the 33 MB y1 round-trip).
// ---------------------------------------------------------------------------
__global__ __launch_bounds__(256, 2) void dense1_mask_mfma(
    const _Float16* __restrict__ s1,
    const _Float16* __restrict__ wdh, const _Float16* __restrict__ wdl,
    unsigned long long* __restrict__ M2g)
{
    __shared__ _Float16 SMEM[32768];     // staging uses 48 KB; y-tile uses all 64 KB
    _Float16 (*As)[128][8] = reinterpret_cast<_Float16(*)[128][8]>(SMEM);
    _Float16 (*Bh)[128][8] = reinterpret_cast<_Float16(*)[128][8]>(SMEM + 8192);
    _Float16 (*Bl)[128][8] = reinterpret_cast<_Float16(*)[128][8]>(SMEM + 16384);

    const int tid = threadIdx.x;
    const int bm = blockIdx.x, bn = blockIdx.y;
    const int lr = tid & 127;
    const int h  = tid >> 7;

    const int n0 = bm * 2;
    const int an = lr >> 6, at = lr & 63;
    // pad row at=63 reads past this n's rows (next n / workspace) — results discarded
    const _Float16* pA  = s1  + ((size_t)(n0 + an) * 63 + at) * 256 + h * 8;
    const _Float16* pBh = wdh + (size_t)(bn * 128 + lr) * 256 + h * 8;
    const _Float16* pBl = wdl + (size_t)(bn * 128 + lr) * 256 + h * 8;

    const int lane = tid & 63;
    const int wv   = tid >> 6;
    const int mw   = wv & 1, nw = wv >> 1;
    const int quad = lane >> 4;
    const int l15  = lane & 15;

    floatx4 accA[4][4] = {};
    floatx4 accB[4][4] = {};

    for (int it = 0; it < 4; ++it) {
        __syncthreads();
#pragma unroll
        for (int q = 0; q < 4; ++q) {
            lds_dma16(pA  + q * 16, &As[q*2 + h][lr][0]);
            lds_dma16(pBh + q * 16, &Bh[q*2 + h][lr][0]);
            lds_dma16(pBl + q * 16, &Bl[q*2 + h][lr][0]);
        }
        __syncthreads();

#pragma unroll
        for (int ks = 0; ks < 2; ++ks) {
            half8 fa[4], fbh[4], fbl[4];
#pragma unroll
            for (int t = 0; t < 4; ++t) {
                fa[t]  = *(const half8*)&As[ks*4 + quad][mw*64 + t*16 + l15][0];
                fbh[t] = *(const half8*)&Bh[ks*4 + quad][nw*64 + t*16 + l15][0];
                fbl[t] = *(const half8*)&Bl[ks*4 + quad][nw*64 + t*16 + l15][0];
            }
#pragma unroll
            for (int ti = 0; ti < 4; ++ti)
#pragma unroll
                for (int tj = 0; tj < 4; ++tj) {
                    accA[ti][tj] = __builtin_amdgcn_mfma_f32_16x16x32_f16(fa[ti], fbh[tj], accA[ti][tj], 0, 0, 0);
                    accB[ti][tj] = __builtin_amdgcn_mfma_f32_16x16x32_f16(fa[ti], fbl[tj], accB[ti][tj], 0, 0, 0);
                }
        }
        pA += 64; pBh += 64; pBl += 64;
    }

    // ---- fused epilogue: y tile -> LDS, cuba2 scan -> spike mask ----
    __syncthreads();
    float* yt = (float*)SMEM;
#pragma unroll
    for (int tj = 0; tj < 4; ++tj) {
        const int cl = nw*64 + tj*16 + l15;
#pragma unroll
        for (int ti = 0; ti < 4; ++ti) {
            const int m0 = mw*64 + ti*16 + quad*4;
#pragma unroll
            for (int r = 0; r < 4; ++r)
                yt[(m0 + r) * 128 + cl] =
                    accA[ti][tj][r] + accB[ti][tj][r] * (1.0f/2048.0f);
        }
    }
    __syncthreads();

    const int nl   = tid >> 7;
    const int oloc = tid & 127;
    unsigned long long mask = 0ull;
    float v = 0.f;
    for (int t = 0; t < 63; ++t) {
        float yv = yt[(nl*64 + t) * 128 + oloc];
        v = 0.9f * v + yv;               // cd=0 -> i = x
        if ((v - 0.1f) >= 0.f) { mask |= (1ull << t); v = 0.f; }
    }
    M2g[(size_t)(n0 + nl) * 256 + bn*128 + oloc] = mask;
}

// ---------------------------------------------------------------------------
// K4: tail — dense2 over spike masks + cuba3 -> out. Reads 2 KB/block.
// ---------------------------------------------------------------------------
__global__ __launch_bounds__(256) void snn_tail(
    const unsigned long long* __restrict__ M2g, const float* __restrict__ w2,
    float* __restrict__ out)
{
    __shared__ unsigned long long M2[256];
    __shared__ float Y[2 * 63];
    const int n   = blockIdx.x;
    const int tid = threadIdx.x;

    M2[tid] = M2g[(size_t)n * 256 + tid];
    __syncthreads();

    if (tid < 126) {
        const int cls = tid / 63;
        const int t   = tid - cls * 63;
        const float* wrow = w2 + cls * 256;
        float acc = 0.f;
#pragma unroll 4
        for (int o = 0; o < 256; ++o)
            acc += ((M2[o] >> t) & 1ull) ? wrow[o] : 0.f;
        Y[cls * 63 + t] = acc;
    }
    __syncthreads();
    if (tid < 2) {
        float v = 0.f;
        float* orow = out + (size_t)n * 126 + tid * 63;
        for (int t = 0; t < 63; ++t) {
            v = 0.9f * v + Y[tid * 63 + t];
            float u = v - 0.1f;
            float s = (u >= 0.f) ? 1.f : 0.f;
            orow[t] = s;
            v = (u >= 0.f) ? 0.f : v;
        }
    }
}

// ---------------------------------------------------------------------------
extern "C" void kernel_launch(void* const* d_in, const int* in_sizes, int n_in,
                              void* d_out, int out_size, void* d_ws, size_t ws_size,
                              hipStream_t stream)
{
    const float* x    = (const float*)d_in[0];
    const float* c1w  = (const float*)d_in[1];
    const float* c1b  = (const float*)d_in[2];
    const float* g1   = (const float*)d_in[3];
    const float* b1   = (const float*)d_in[4];
    const float* m1   = (const float*)d_in[5];
    const float* v1   = (const float*)d_in[6];
    const float* c2w  = (const float*)d_in[7];
    const float* c2b  = (const float*)d_in[8];
    const float* g2   = (const float*)d_in[9];
    const float* b2   = (const float*)d_in[10];
    const float* m2   = (const float*)d_in[11];
    const float* v2   = (const float*)d_in[12];
    const float* w1   = (const float*)d_in[13];
    const float* w2   = (const float*)d_in[14];
    float* out = (float*)d_out;

    float* ws = (float*)d_ws;
    // layout (float units):
    //   [0,        4325376)   z1ph  (padded [512][66][256] fp16)
    //   [4325376,  8650752)   z1pl
    //   [8650752, 12779520)   s1    ([512][63][256] fp16)
    //   [12779520,13041664)   M2g   ([512][256] u64 = 1 MB)
    //   [13041664, ...)       weight limbs + ab
    _Float16* z1ph = (_Float16*)ws;
    _Float16* z1pl = (_Float16*)(ws + 4325376);
    _Float16* s1   = (_Float16*)(ws + 8650752);
    unsigned long long* M2g = (unsigned long long*)(ws + 12779520);
    float*    wsp  = ws + 13041664;
    _Float16* w1h = (_Float16*)wsp;                                 // 262,144 f
    _Float16* w1l = (_Float16*)(wsp + 262144);                      // 262,144 f
    _Float16* w2h = (_Float16*)(wsp + 2*262144);                    //  98,304 f
    _Float16* w2l = (_Float16*)(wsp + 2*262144 + 98304);            //  98,304 f
    _Float16* wdh = (_Float16*)(wsp + 2*262144 + 2*98304);          //  32,768 f
    _Float16* wdl = (_Float16*)(wsp + 2*262144 + 2*98304 + 32768);  //  32,768 f
    float*    ab1 = wsp + 2*262144 + 2*98304 + 2*32768;
    float*    ab2 = ab1 + 512;

    prep_kernel<<<256, 256, 0, stream>>>(c1w, c1b, g1, b1, m1, v1,
                                         c2w, c2b, g2, b2, m2, v2,
                                         w1, w1h, w1l, w2h, w2l, wdh, wdl,
                                         z1ph, z1pl, ab1, ab2);
    conv1_mfma<<<dim3(252, 2), 256, 0, stream>>>(x, w1h, w1l, ab1, z1ph, z1pl);
    conv2_cuba_mfma<<<dim3(256, 2), 256, 0, stream>>>(z1ph, z1pl, w2h, w2l, ab2, s1);
    dense1_mask_mfma<<<dim3(256, 2), 256, 0, stream>>>(s1, wdh, wdl, M2g);
    snn_tail<<<512, 256, 0, stream>>>(M2g, w2, out);
}